// Round 11
// baseline (274.463 us; speedup 1.0000x reference)
//
#include <hip/hip_runtime.h>
#include <math.h>

// Problem constants: B=512, C=50000, D=256.
#define D_DIM 256
#define GTM 64    // gemm tile M
#define GTN 64    // gemm tile N
#define BK 32     // K-tile depth (bf16); 8 K-iterations
#define NB 782    // n-blocks (50000/64 rounded up)
#define NBP 784   // padded partial stride
#define CBPR 4    // compress blocks per row (4*16384 cols = 65536 >= 50000)
#define CBLKS (CBPR * 512)   // 2048 compress-role blocks

typedef __attribute__((ext_vector_type(8))) short short8;
typedef __attribute__((ext_vector_type(4))) float floatx4;
typedef unsigned long long u64;

__device__ __forceinline__ unsigned short f2bf(float f) {
    unsigned int u = __float_as_uint(f);
    u += 0x7FFFu + ((u >> 16) & 1u);   // round-to-nearest-even
    return (unsigned short)(u >> 16);
}

// async global->LDS 16B: lane l's 16B lands at ldsbase + l*16 (wave-uniform base)
__device__ __forceinline__ void gload16(const void* g, void* lds) {
    __builtin_amdgcn_global_load_lds(
        (const __attribute__((address_space(1))) unsigned int*)g,
        (__attribute__((address_space(3))) unsigned int*)lds, 16, 0, 0);
}

// ---- kernel 1: fused label-compress (role A) + norms/bf16-convert/loadedmask (role B)
// Compress: 16 int4 loads register-batched (256 B/lane in flight -> deep MLP), then
// LDS nibble transpose, then 2 coalesced u32 stores per thread.
__global__ __launch_bounds__(256) void prep_compress(
    const float* __restrict__ V, const float* __restrict__ T,
    const int* __restrict__ label, const int* __restrict__ ids,
    u64* __restrict__ loadedmask, u64* __restrict__ posmask,
    unsigned short* __restrict__ Vb, unsigned short* __restrict__ Tb,
    float* __restrict__ gaccum, unsigned int* __restrict__ gcount,
    int B, int C, int n_loaded, int WPR) {
    const int bid = blockIdx.x;
    const int tid = threadIdx.x;
    const int lane = tid & 63;

    if (bid < CBLKS) {   // ---- compress role: 102 MB label stream -> 3.2 MB raw posmask
        __shared__ unsigned char nib[4096];   // nibble n covers cols cbase+4n..+3
        int row = bid / CBPR;
        int sub = bid - row * CBPR;
        int cbase = sub * 16384;              // this block's 16384-col window
        const int* lp = label + (size_t)row * C;
        int4 q[16];                           // 16 loads in flight: 256 B/lane
        #pragma unroll
        for (int j = 0; j < 16; ++j) {
            int col = cbase + j * 1024 + tid * 4;
            if (col < C) q[j] = *(const int4*)(lp + col);   // C%4==0: full chunk valid
            else         q[j] = make_int4(0, 0, 0, 0);
        }
        #pragma unroll
        for (int j = 0; j < 16; ++j) {
            unsigned int n = (q[j].x ? 1u : 0u) | (q[j].y ? 2u : 0u) |
                             (q[j].z ? 4u : 0u) | (q[j].w ? 8u : 0u);
            nib[j * 256 + tid] = (unsigned char)n;
        }
        __syncthreads();
        #pragma unroll
        for (int h = 0; h < 2; ++h) {         // 512 u32 words per block, 2 per thread
            int widx = h * 256 + tid;
            u64 nb8 = *(const u64*)&nib[widx * 8];  // 8 nibbles = 32 cols
            unsigned int word = 0;
            #pragma unroll
            for (int j = 0; j < 8; ++j)
                word |= ((unsigned int)((nb8 >> (8 * j)) & 0xFu)) << (4 * j);
            int u32idx = sub * 512 + widx;    // u32 slot within the row
            if (u32idx < 2 * WPR)             // little-endian pairs == u64 mask words
                ((unsigned int*)(posmask + (size_t)row * WPR))[u32idx] = word;
        }
        return;
    }

    // ---- prep role: loadedmask (binary search over sorted ids) + normalize -> bf16
    int ptid = (bid - CBLKS) * 256 + tid;
    if (ptid == 0) { *gcount = 0u; *gaccum = 0.f; }   // zero reduce scratch each call
    if (ptid < WPR) {
        int base = ptid << 6;
        int lo = 0, hi = n_loaded;
        while (lo < hi) { int mid = (lo + hi) >> 1; if (ids[mid] < base) lo = mid + 1; else hi = mid; }
        u64 m = 0;
        for (int i = lo; i < n_loaded; ++i) {
            int v = ids[i]; if (v >= base + 64) break;
            m |= 1ull << (v - base);
        }
        loadedmask[ptid] = m;
    }
    // four rows per wave: 4 loads in flight, 4 independent butterflies
    int pwave = (bid - CBLKS) * 4 + (tid >> 6);
    int r0 = pwave * 4;
    if (r0 >= B + C) return;
    float4 x[4];
    #pragma unroll
    for (int q = 0; q < 4; ++q) {
        int wv = r0 + q;
        if (wv < B + C) {
            const float* src = (wv < B) ? (V + (size_t)wv * D_DIM)
                                        : (T + (size_t)(wv - B) * D_DIM);
            x[q] = ((const float4*)src)[lane];
        }
    }
    #pragma unroll
    for (int q = 0; q < 4; ++q) {
        int wv = r0 + q;
        if (wv >= B + C) break;
        bool isV = wv < B;
        float ss = x[q].x * x[q].x + x[q].y * x[q].y + x[q].z * x[q].z + x[q].w * x[q].w;
        #pragma unroll
        for (int off = 32; off > 0; off >>= 1) ss += __shfl_xor(ss, off);
        float nrm = sqrtf(ss);
        float s = isV ? (1.0f / nrm) : (1.0f / (1e-6f + nrm));  // eps on text norms only
        ushort4 o;
        o.x = f2bf(x[q].x * s); o.y = f2bf(x[q].y * s);
        o.z = f2bf(x[q].z * s); o.w = f2bf(x[q].w * s);
        unsigned short* dst = isV ? (Vb + (size_t)wv * D_DIM)
                                  : (Tb + (size_t)(wv - B) * D_DIM);
        ((ushort4*)dst)[lane] = o;
    }
}

// ---- kernel 2: 64x64-tile bf16 MFMA + raw-posmask epilogue --------------------------
// grid = (8, 782), m fastest: co-resident blocks share B-tiles in L2. Small tiles ->
// acc = 16 VGPR/wave -> high occupancy; all data L2/L3-resident after kernel 1.
__global__ __launch_bounds__(256) void gemm_fused(
    const unsigned short* __restrict__ Vb, const unsigned short* __restrict__ Tb,
    const u64* __restrict__ posmask, const u64* __restrict__ loadedmask,
    float* __restrict__ denomP, float* __restrict__ posP, int C, int WPR) {
    __shared__ unsigned short As[GTM * BK];   // 4 KB, [row][32] (global_load_lds layout)
    __shared__ unsigned short Bs[GTN * BK];   // 4 KB
    __shared__ float sDen[GTM], sPos[GTM];

    const int tid  = threadIdx.x;
    const int lane = tid & 63;
    const int w    = tid >> 6;
    const int m0 = blockIdx.x * GTM;
    const int n0 = blockIdx.y * GTN;

    if (tid < GTM) { sDen[tid] = 0.f; sPos[tid] = 0.f; }

    // ---- staging: wave w stages 16 rows of A and of B per K-tile (1 gload16 each)
    const int sra = lane >> 2;          // row within 16-row group
    const int kc  = (lane & 3) * 8;     // 16B k-chunk
    int ga = m0 + w * 16 + sra;
    int gb = n0 + w * 16 + sra;
    if (gb >= C) gb = C - 1;            // OOB rows: valid address, masked in epilogue
    const unsigned short* gA = Vb + (size_t)ga * D_DIM + kc;
    const unsigned short* gB = Tb + (size_t)gb * D_DIM + kc;
    unsigned short* lA = &As[w * 16 * BK];
    unsigned short* lB = &Bs[w * 16 * BK];

    // ---- compute mapping: 2x2 waves, each 32x32 via 2x2 frags of 16x16x32
    const int wm = (w >> 1) * 32;
    const int wn = (w & 1) * 32;
    const int fr = lane & 15;
    const int quad = lane >> 4;

    floatx4 acc[2][2];
    #pragma unroll
    for (int mi = 0; mi < 2; mi++)
        #pragma unroll
        for (int ni = 0; ni < 2; ni++) acc[mi][ni] = (floatx4)0.f;

    #pragma unroll
    for (int kt = 0; kt < D_DIM / BK; ++kt) {
        if (kt) __syncthreads();
        gload16(gA + kt * BK, lA);
        gload16(gB + kt * BK, lB);
        __syncthreads();                // drains vmcnt before barrier
        short8 af[2], bf[2];
        #pragma unroll
        for (int mi = 0; mi < 2; mi++)
            af[mi] = *(const short8*)&As[(wm + mi * 16 + fr) * BK + quad * 8];
        #pragma unroll
        for (int ni = 0; ni < 2; ni++)
            bf[ni] = *(const short8*)&Bs[(wn + ni * 16 + fr) * BK + quad * 8];
        #pragma unroll
        for (int mi = 0; mi < 2; mi++)
            #pragma unroll
            for (int ni = 0; ni < 2; ni++)
                acc[mi][ni] = __builtin_amdgcn_mfma_f32_16x16x32_bf16(
                    af[mi], bf[ni], acc[mi][ni], 0, 0, 0);
    }

    // ---- epilogue: D layout row = quad*4 + reg, col = lane&15 per 16x16 frag.
    const int wordIdx = n0 >> 6;              // whole block = one 64-col mask word
    const u64 loadedw = loadedmask[wordIdx];
    #pragma unroll
    for (int mi = 0; mi < 2; mi++) {
        #pragma unroll
        for (int i = 0; i < 4; i++) {
            const int mloc = wm + mi * 16 + quad * 4 + i;
            const u64 praw = posmask[(size_t)(m0 + mloc) * WPR + wordIdx];  // L2-hit
            const u64 posw = praw & loadedw;
            const u64 negw = loadedw & ~praw;
            float den = 0.f, pos = 0.f;
            #pragma unroll
            for (int ni = 0; ni < 2; ni++) {
                const float s = acc[mi][ni][i];
                const int bit = wn + ni * 16 + fr;
                if ((negw >> bit) & 1) den += __expf(s);
                if ((posw >> bit) & 1) pos += s;
            }
            #pragma unroll
            for (int off = 8; off >= 1; off >>= 1) {   // reduce 16-lane quad row
                den += __shfl_xor(den, off);
                pos += __shfl_xor(pos, off);
            }
            if (fr == 0) {
                if (den != 0.f) atomicAdd(&sDen[mloc], den);
                if (pos != 0.f) atomicAdd(&sPos[mloc], pos);
            }
        }
    }
    __syncthreads();
    if (tid < GTM) {   // row-major partials: [row][n-block] for coalesced reduce
        denomP[(size_t)(m0 + tid) * NBP + blockIdx.y] = sDen[tid];
        posP[(size_t)(m0 + tid) * NBP + blockIdx.y]   = sPos[tid];
    }
}

// ---- kernel 3: reduce rows + last-block computes the final mean ---------------------
__global__ void reduce_rows(const float* __restrict__ denomP, const float* __restrict__ posP,
                            const u64* __restrict__ posmask, const u64* __restrict__ loadedmask,
                            float* __restrict__ gaccum, unsigned int* __restrict__ gcount,
                            float* __restrict__ out, int B, int WPR) {
    __shared__ float bsum[4];
    int wv   = threadIdx.x >> 6;
    int row  = blockIdx.x * 4 + wv;
    int lane = threadIdx.x & 63;
    float den = 0.f, pos = 0.f;
    int cnt = 0;
    if (row < B) {
        for (int bn = lane; bn < NB; bn += 64) {   // contiguous within row: coalesced
            den += denomP[(size_t)row * NBP + bn];
            pos += posP[(size_t)row * NBP + bn];
        }
        for (int j = lane; j < WPR; j += 64)
            cnt += __popcll(posmask[(size_t)row * WPR + j] & loadedmask[j]);
        #pragma unroll
        for (int off = 32; off > 0; off >>= 1) {
            den += __shfl_xor(den, off);
            pos += __shfl_xor(pos, off);
            cnt += __shfl_xor(cnt, off);
        }
    }
    if (lane == 0) bsum[wv] = (row < B) ? (logf(den) - pos / (float)cnt) : 0.f;
    __syncthreads();
    if (threadIdx.x == 0) {
        float s = bsum[0] + bsum[1] + bsum[2] + bsum[3];
        atomicAdd(gaccum, s);            // 128 ops total: contention negligible
        __threadfence();
        unsigned int old = atomicAdd(gcount, 1u);
        if (old == gridDim.x - 1) {      // last block: all adds complete & visible
            float tot = atomicAdd(gaccum, 0.0f);   // atomic read-back
            out[0] = tot / (float)B;
        }
    }
}

extern "C" void kernel_launch(void* const* d_in, const int* in_sizes, int n_in,
                              void* d_out, int out_size, void* d_ws, size_t ws_size,
                              hipStream_t stream) {
    const float* V     = (const float*)d_in[0];
    const float* T     = (const float*)d_in[1];
    const int*   label = (const int*)d_in[2];
    const int*   ids   = (const int*)d_in[3];
    int B = in_sizes[0] / D_DIM;   // 512
    int C = in_sizes[1] / D_DIM;   // 50000
    int n_loaded = in_sizes[3];    // 40000
    int WPR = (C + 63) >> 6;       // mask words per row (782)

    // ws layout (bytes):
    //   0        : gaccum [1 f], gcount [1 u32]    (pad to 2048)
    //   2048     : loadedmask [782 u64]            (ends 8304; pad to 8320)
    //   8320     : posmask [512*782 u64]           (3,203,072 -> ends 3,211,392)
    //   3211392  : Vb [512*256 bf16]               (262,144 -> ends 3,473,536)
    //   3473536  : Tb [50000*256 bf16]             (25.6 MB -> ends 29,073,536)
    //   29073536 : denomP [512*784 f]              (1,605,632 -> ends 30,679,168)
    //   30679168 : posP                            (ends 32,284,800)
    char* ws = (char*)d_ws;
    float*        gaccum = (float*)(ws + 0);
    unsigned int* gcount = (unsigned int*)(ws + 8);
    u64*   loadedmask = (u64*)(ws + 2048);
    u64*   posmask    = (u64*)(ws + 8320);
    unsigned short* Vb = (unsigned short*)(ws + 3211392);
    unsigned short* Tb = (unsigned short*)(ws + 3473536);
    float* denomP  = (float*)(ws + 29073536);
    float* posP    = (float*)(ws + 30679168);

    int prep_waves  = (B + C + 3) / 4;                  // 4 rows per wave
    int prep_blocks = (prep_waves + 3) / 4;             // 3158
    prep_compress<<<CBLKS + prep_blocks, 256, 0, stream>>>(
        V, T, label, ids, loadedmask, posmask, Vb, Tb, gaccum, gcount,
        B, C, n_loaded, WPR);

    dim3 grid(B / GTM, NB);   // m fastest: 8 blocks share one T-tile
    gemm_fused<<<grid, 256, 0, stream>>>(Vb, Tb, posmask, loadedmask,
                                         denomP, posP, C, WPR);

    reduce_rows<<<(B + 3) / 4, 256, 0, stream>>>(denomP, posP, posmask, loadedmask,
                                                 gaccum, gcount, (float*)d_out, B, WPR);
}

// Round 12
// 269.002 us; speedup vs baseline: 1.0203x; 1.0203x over previous
//
#include <hip/hip_runtime.h>
#include <math.h>

// Problem constants: B=512, C=50000, D=256.
#define D_DIM 256
#define GTM 64    // gemm tile M
#define GTN 64    // gemm tile N
#define BK 32     // K-tile depth (bf16); 8 K-iterations
#define NB 782    // n-blocks (50000/64 rounded up)
#define NBP 784   // padded partial stride

typedef __attribute__((ext_vector_type(8))) short short8;
typedef __attribute__((ext_vector_type(4))) float floatx4;
typedef unsigned long long u64;

__device__ __forceinline__ unsigned short f2bf(float f) {
    unsigned int u = __float_as_uint(f);
    u += 0x7FFFu + ((u >> 16) & 1u);   // round-to-nearest-even
    return (unsigned short)(u >> 16);
}

// async global->LDS 16B: lane l's 16B lands at ldsbase + l*16 (wave-uniform base)
__device__ __forceinline__ void gload16(const void* g, void* lds) {
    __builtin_amdgcn_global_load_lds(
        (const __attribute__((address_space(1))) unsigned int*)g,
        (__attribute__((address_space(3))) unsigned int*)lds, 16, 0, 0);
}

// ---- kernel 1: prep — loadedmask (binary search over sorted ids) + normalize -> bf16
__global__ __launch_bounds__(256) void prep(
    const float* __restrict__ V, const float* __restrict__ T,
    const int* __restrict__ ids, u64* __restrict__ loadedmask,
    unsigned short* __restrict__ Vb, unsigned short* __restrict__ Tb,
    float* __restrict__ gaccum, unsigned int* __restrict__ gcount,
    int B, int C, int n_loaded, int WPR) {
    const int tid = threadIdx.x;
    const int lane = tid & 63;
    int ptid = blockIdx.x * 256 + tid;
    if (ptid == 0) { *gcount = 0u; *gaccum = 0.f; }   // zero reduce scratch each call
    if (ptid < WPR) {
        int base = ptid << 6;
        int lo = 0, hi = n_loaded;
        while (lo < hi) { int mid = (lo + hi) >> 1; if (ids[mid] < base) lo = mid + 1; else hi = mid; }
        u64 m = 0;
        for (int i = lo; i < n_loaded; ++i) {
            int v = ids[i]; if (v >= base + 64) break;
            m |= 1ull << (v - base);
        }
        loadedmask[ptid] = m;
    }
    // four rows per wave: 4 loads in flight, 4 independent butterflies
    int pwave = blockIdx.x * 4 + (tid >> 6);
    int r0 = pwave * 4;
    if (r0 >= B + C) return;
    float4 x[4];
    #pragma unroll
    for (int q = 0; q < 4; ++q) {
        int wv = r0 + q;
        if (wv < B + C) {
            const float* src = (wv < B) ? (V + (size_t)wv * D_DIM)
                                        : (T + (size_t)(wv - B) * D_DIM);
            x[q] = ((const float4*)src)[lane];
        }
    }
    #pragma unroll
    for (int q = 0; q < 4; ++q) {
        int wv = r0 + q;
        if (wv >= B + C) break;
        bool isV = wv < B;
        float ss = x[q].x * x[q].x + x[q].y * x[q].y + x[q].z * x[q].z + x[q].w * x[q].w;
        #pragma unroll
        for (int off = 32; off > 0; off >>= 1) ss += __shfl_xor(ss, off);
        float nrm = sqrtf(ss);
        float s = isV ? (1.0f / nrm) : (1.0f / (1e-6f + nrm));  // eps on text norms only
        ushort4 o;
        o.x = f2bf(x[q].x * s); o.y = f2bf(x[q].y * s);
        o.z = f2bf(x[q].z * s); o.w = f2bf(x[q].w * s);
        unsigned short* dst = isV ? (Vb + (size_t)wv * D_DIM)
                                  : (Tb + (size_t)(wv - B) * D_DIM);
        ((ushort4*)dst)[lane] = o;
    }
}

// ---- kernel 2: 64x64-tile bf16 MFMA + IN-BLOCK label ballot + masked epilogue ------
// Each block reads its own 64x64 label patch (16 KB, ballot -> LDS smask[64]); the
// 102 MB label stream thus overlaps the MFMA K-loops of co-resident waves/blocks.
// grid = (8, 782), m fastest: co-resident blocks share one B-tile (L2/L3 reuse).
__global__ __launch_bounds__(256) void gemm_fused(
    const unsigned short* __restrict__ Vb, const unsigned short* __restrict__ Tb,
    const int* __restrict__ label, const u64* __restrict__ loadedmask,
    float* __restrict__ denomP, float* __restrict__ posP, float* __restrict__ npP,
    int C, int WPR) {
    __shared__ unsigned short As[GTM * BK];   // 4 KB, [row][32] (global_load_lds layout)
    __shared__ unsigned short Bs[GTN * BK];   // 4 KB
    __shared__ u64 smask[GTM];                // raw label bits, one word per tile row
    __shared__ float sDen[GTM], sPos[GTM], sNp[GTM];

    const int tid  = threadIdx.x;
    const int lane = tid & 63;
    const int w    = tid >> 6;
    const int m0 = blockIdx.x * GTM;
    const int n0 = blockIdx.y * GTN;

    if (tid < GTM) { sDen[tid] = 0.f; sPos[tid] = 0.f; sNp[tid] = 0.f; }

    // ---- label phase: wave w ballots rows [w*16, w*16+16); lane = col within patch
    {
        int col = n0 + lane;
        if (col >= C) col = C - 1;            // clamped; loadedmask bit is 0 there
        const int* lp = label + (size_t)(m0 + w * 16) * C + col;
        int labv[16];
        #pragma unroll
        for (int i = 0; i < 16; ++i) labv[i] = lp[(size_t)i * C];   // coalesced 256B/row
        #pragma unroll
        for (int i = 0; i < 16; ++i) {
            u64 bw = __ballot(labv[i] != 0);
            if (lane == 0) smask[w * 16 + i] = bw;
        }
    }

    // ---- staging: wave w stages 16 rows of A and of B per K-tile (1 gload16 each)
    const int sra = lane >> 2;          // row within 16-row group
    const int kc  = (lane & 3) * 8;     // 16B k-chunk
    int ga = m0 + w * 16 + sra;
    int gb = n0 + w * 16 + sra;
    if (gb >= C) gb = C - 1;            // OOB rows: valid address, masked in epilogue
    const unsigned short* gA = Vb + (size_t)ga * D_DIM + kc;
    const unsigned short* gB = Tb + (size_t)gb * D_DIM + kc;
    unsigned short* lA = &As[w * 16 * BK];
    unsigned short* lB = &Bs[w * 16 * BK];

    // ---- compute mapping: 2x2 waves, each 32x32 via 2x2 frags of 16x16x32
    const int wm = (w >> 1) * 32;
    const int wn = (w & 1) * 32;
    const int fr = lane & 15;
    const int quad = lane >> 4;

    floatx4 acc[2][2];
    #pragma unroll
    for (int mi = 0; mi < 2; mi++)
        #pragma unroll
        for (int ni = 0; ni < 2; ni++) acc[mi][ni] = (floatx4)0.f;

    #pragma unroll
    for (int kt = 0; kt < D_DIM / BK; ++kt) {
        if (kt) __syncthreads();
        gload16(gA + kt * BK, lA);
        gload16(gB + kt * BK, lB);
        __syncthreads();                // drains vmcnt before barrier
        short8 af[2], bf[2];
        #pragma unroll
        for (int mi = 0; mi < 2; mi++)
            af[mi] = *(const short8*)&As[(wm + mi * 16 + fr) * BK + quad * 8];
        #pragma unroll
        for (int ni = 0; ni < 2; ni++)
            bf[ni] = *(const short8*)&Bs[(wn + ni * 16 + fr) * BK + quad * 8];
        #pragma unroll
        for (int mi = 0; mi < 2; mi++)
            #pragma unroll
            for (int ni = 0; ni < 2; ni++)
                acc[mi][ni] = __builtin_amdgcn_mfma_f32_16x16x32_bf16(
                    af[mi], bf[ni], acc[mi][ni], 0, 0, 0);
    }

    // ---- epilogue: D layout row = quad*4 + reg, col = lane&15 per 16x16 frag.
    const u64 loadedw = loadedmask[n0 >> 6];  // block's 64-col window = one word
    #pragma unroll
    for (int mi = 0; mi < 2; mi++) {
        #pragma unroll
        for (int i = 0; i < 4; i++) {
            const int mloc = wm + mi * 16 + quad * 4 + i;
            const u64 praw = smask[mloc];     // LDS broadcast within quad row
            const u64 posw = praw & loadedw;
            const u64 negw = loadedw & ~praw;
            float den = 0.f, pos = 0.f, np = 0.f;
            #pragma unroll
            for (int ni = 0; ni < 2; ni++) {
                const float s = acc[mi][ni][i];
                const int bit = wn + ni * 16 + fr;
                if ((negw >> bit) & 1) den += __expf(s);
                if ((posw >> bit) & 1) { pos += s; np += 1.f; }
            }
            #pragma unroll
            for (int off = 8; off >= 1; off >>= 1) {   // reduce 16-lane quad row
                den += __shfl_xor(den, off);
                pos += __shfl_xor(pos, off);
                np  += __shfl_xor(np, off);
            }
            if (fr == 0) {
                if (den != 0.f) atomicAdd(&sDen[mloc], den);
                if (np  != 0.f) { atomicAdd(&sPos[mloc], pos); atomicAdd(&sNp[mloc], np); }
            }
        }
    }
    __syncthreads();
    if (tid < GTM) {   // row-major partials: [row][n-block] for coalesced reduce
        denomP[(size_t)(m0 + tid) * NBP + blockIdx.y] = sDen[tid];
        posP[(size_t)(m0 + tid) * NBP + blockIdx.y]   = sPos[tid];
        npP[(size_t)(m0 + tid) * NBP + blockIdx.y]    = sNp[tid];
    }
}

// ---- kernel 3: reduce rows + last-block computes the final mean ---------------------
__global__ void reduce_rows(const float* __restrict__ denomP, const float* __restrict__ posP,
                            const float* __restrict__ npP,
                            float* __restrict__ gaccum, unsigned int* __restrict__ gcount,
                            float* __restrict__ out, int B) {
    __shared__ float bsum[4];
    int wv   = threadIdx.x >> 6;
    int row  = blockIdx.x * 4 + wv;
    int lane = threadIdx.x & 63;
    float den = 0.f, pos = 0.f, np = 0.f;
    if (row < B) {
        for (int bn = lane; bn < NB; bn += 64) {   // contiguous within row: coalesced
            den += denomP[(size_t)row * NBP + bn];
            pos += posP[(size_t)row * NBP + bn];
            np  += npP[(size_t)row * NBP + bn];
        }
        #pragma unroll
        for (int off = 32; off > 0; off >>= 1) {
            den += __shfl_xor(den, off);
            pos += __shfl_xor(pos, off);
            np  += __shfl_xor(np, off);
        }
    }
    if (lane == 0) bsum[wv] = (row < B) ? (logf(den) - pos / np) : 0.f;
    __syncthreads();
    if (threadIdx.x == 0) {
        float s = bsum[0] + bsum[1] + bsum[2] + bsum[3];
        atomicAdd(gaccum, s);            // 128 ops total: contention negligible
        __threadfence();
        unsigned int old = atomicAdd(gcount, 1u);
        if (old == gridDim.x - 1) {      // last block: all adds complete & visible
            float tot = atomicAdd(gaccum, 0.0f);   // atomic read-back
            out[0] = tot / (float)B;
        }
    }
}

extern "C" void kernel_launch(void* const* d_in, const int* in_sizes, int n_in,
                              void* d_out, int out_size, void* d_ws, size_t ws_size,
                              hipStream_t stream) {
    const float* V     = (const float*)d_in[0];
    const float* T     = (const float*)d_in[1];
    const int*   label = (const int*)d_in[2];
    const int*   ids   = (const int*)d_in[3];
    int B = in_sizes[0] / D_DIM;   // 512
    int C = in_sizes[1] / D_DIM;   // 50000
    int n_loaded = in_sizes[3];    // 40000
    int WPR = (C + 63) >> 6;       // mask words per row (782)

    // ws layout (bytes):
    //   0        : gaccum [1 f], gcount [1 u32]    (pad to 2048)
    //   2048     : loadedmask [782 u64]            (ends 8304; pad to 8320)
    //   8320     : Vb [512*256 bf16]               (262,144 -> ends 270,464)
    //   270464   : Tb [50000*256 bf16]             (25.6 MB -> ends 25,870,464)
    //   25870464 : denomP [512*784 f]              (1,605,632 -> ends 27,476,096)
    //   27476096 : posP                            (ends 29,081,728)
    //   29081728 : npP                             (ends 30,687,360)
    char* ws = (char*)d_ws;
    float*        gaccum = (float*)(ws + 0);
    unsigned int* gcount = (unsigned int*)(ws + 8);
    u64*   loadedmask = (u64*)(ws + 2048);
    unsigned short* Vb = (unsigned short*)(ws + 8320);
    unsigned short* Tb = (unsigned short*)(ws + 270464);
    float* denomP  = (float*)(ws + 25870464);
    float* posP    = (float*)(ws + 27476096);
    float* npP     = (float*)(ws + 29081728);

    int prep_waves  = (B + C + 3) / 4;                  // 4 rows per wave
    int prep_blocks = (prep_waves + 3) / 4;             // 3158
    prep<<<prep_blocks, 256, 0, stream>>>(
        V, T, ids, loadedmask, Vb, Tb, gaccum, gcount, B, C, n_loaded, WPR);

    dim3 grid(B / GTM, NB);   // m fastest: 8 blocks share one T-tile
    gemm_fused<<<grid, 256, 0, stream>>>(Vb, Tb, label, loadedmask,
                                         denomP, posP, npP, C, WPR);

    reduce_rows<<<(B + 3) / 4, 256, 0, stream>>>(denomP, posP, npP,
                                                 gaccum, gcount, (float*)d_out, B);
}